// Round 7
// baseline (276.144 us; speedup 1.0000x reference)
//
#include <hip/hip_runtime.h>
#include <math.h>

typedef unsigned short u16;
typedef __attribute__((ext_vector_type(8))) short short8;
typedef __attribute__((ext_vector_type(4))) float f32x4;
typedef __attribute__((ext_vector_type(4))) unsigned short u16x4;
typedef __attribute__((ext_vector_type(8))) unsigned short u16x8;

#define N_TOK 2048
#define DIM 1024
#define OUT_ELEMS 2097152   // N_TOK * DIM

#define GLDS16(gp, lp) __builtin_amdgcn_global_load_lds( \
    (const __attribute__((address_space(1))) unsigned int*)(gp), \
    (__attribute__((address_space(3))) unsigned int*)(lp), 16, 0, 0)

__device__ __forceinline__ u16 f2bf(float f) {
    union { float f; unsigned u; } v; v.f = f;
    unsigned r = (v.u + 0x7FFFu + ((v.u >> 16) & 1u)) >> 16;
    return (u16)r;
}
__device__ __forceinline__ float bf2f(u16 h) {
    union { unsigned u; float f; } v; v.u = ((unsigned)h) << 16;
    return v.f;
}

// -------- init: shared token list, cursors, Psum/cnt zeros ------
__global__ void k_init(int* __restrict__ tlist, int* __restrict__ curs,
                       float* __restrict__ Psum, int* __restrict__ cnt8) {
    int i = blockIdx.x * 256 + threadIdx.x;   // 0..2047
    tlist[4096 + i] = i;
    if (i < 16) curs[i] = 0;
    if (i < 8) { Psum[i] = 0.f; cnt8[i] = 0; }
}

// ------- weights: fp32 [K,N] -> bf16 CHUNK-TRANSPOSED W'[k/8][n][8] -------
__global__ void k_cvt_w(const float* __restrict__ wg, const float* __restrict__ wu,
                        const float* __restrict__ wd, const float* __restrict__ wsg,
                        const float* __restrict__ wsu, const float* __restrict__ wsd,
                        u16* __restrict__ wgt, u16* __restrict__ wut,
                        u16* __restrict__ wdt, u16* __restrict__ wsgt,
                        u16* __restrict__ wsut, u16* __restrict__ wsdt) {
    __shared__ u16 tile[8 * 1024];   // 16 KB
    int bx = blockIdx.x;             // 27 * 128
    int mat = bx >> 7;
    int chunk = bx & 127;            // k-chunk (8 rows)
    const float* src; u16* dst;
    if      (mat <  8) { src = wg  + (size_t)mat * 1048576;        dst = wgt + (size_t)mat * 1048576; }
    else if (mat < 16) { src = wu  + (size_t)(mat - 8) * 1048576;  dst = wut + (size_t)(mat - 8) * 1048576; }
    else if (mat < 24) { src = wd  + (size_t)(mat - 16) * 1048576; dst = wdt + (size_t)(mat - 16) * 1048576; }
    else if (mat == 24){ src = wsg; dst = wsgt; }
    else if (mat == 25){ src = wsu; dst = wsut; }
    else               { src = wsd; dst = wsdt; }
    const float* srow = src + (size_t)chunk * 8192;   // 8 rows of 1024
    u16* dchunk = dst + (size_t)chunk * 8192;         // 16KB contiguous out
    int t = threadIdx.x;
    int r  = t >> 5;                 // 0..7
    int c0 = (t & 31) * 4;           // 0..124
    f32x4 v[8];
#pragma unroll
    for (int j = 0; j < 8; j++)
        v[j] = *(const f32x4*)(srow + r * 1024 + c0 + j * 128);
#pragma unroll
    for (int j = 0; j < 8; j++) {
        u16x4 o;
        o.x = f2bf(v[j].x); o.y = f2bf(v[j].y); o.z = f2bf(v[j].z); o.w = f2bf(v[j].w);
        *(u16x4*)(tile + r * 1024 + c0 + j * 128) = o;
    }
    __syncthreads();
#pragma unroll
    for (int j = 0; j < 4; j++) {
        int n = t + j * 256;
        u16x8 o;
#pragma unroll
        for (int k = 0; k < 8; k++) o[k] = tile[k * 1024 + n];
        *(u16x8*)(dchunk + n * 8) = o;
    }
}

// -------- router: logits, top-2, Psum/counts, fused x->bf16 --------
__global__ void k_router(const float* __restrict__ x, const float* __restrict__ wgate,
                         u16* __restrict__ xb, int* __restrict__ tidx,
                         float* __restrict__ tw, float* __restrict__ Psum,
                         int* __restrict__ cnt8) {
    __shared__ float sP[8];
    __shared__ int   sC[8];
    int t = threadIdx.x;
    if (t < 8) { sP[t] = 0.f; sC[t] = 0; }
    __syncthreads();
    int wave = t >> 6;
    int lane = t & 63;
    int n = blockIdx.x * 4 + wave;
    const float* xr = x + (size_t)n * DIM;
    u16* xbr = xb + (size_t)n * DIM;
    float acc[8] = {0.f,0.f,0.f,0.f,0.f,0.f,0.f,0.f};
#pragma unroll
    for (int i = 0; i < 16; i++) {
        int d = lane + i * 64;
        float xv = xr[d];
        xbr[d] = f2bf(xv);
        const float* wr = wgate + d * 8;
#pragma unroll
        for (int e = 0; e < 8; e++) acc[e] += xv * wr[e];
    }
#pragma unroll
    for (int off = 32; off; off >>= 1) {
#pragma unroll
        for (int e = 0; e < 8; e++) acc[e] += __shfl_xor(acc[e], off);
    }
    if (lane == 0) {
        float mx = acc[0];
#pragma unroll
        for (int e = 1; e < 8; e++) mx = fmaxf(mx, acc[e]);
        float p[8], s = 0.f;
#pragma unroll
        for (int e = 0; e < 8; e++) { p[e] = expf(acc[e] - mx); s += p[e]; }
        float inv = 1.f / s;
#pragma unroll
        for (int e = 0; e < 8; e++) atomicAdd(&sP[e], p[e] * inv);
        int i0 = 0; float b0 = acc[0];
#pragma unroll
        for (int e = 1; e < 8; e++) if (acc[e] > b0) { b0 = acc[e]; i0 = e; }
        int i1 = -1; float b1 = -3.4e38f;
#pragma unroll
        for (int e = 0; e < 8; e++) if (e != i0 && acc[e] > b1) { b1 = acc[e]; i1 = e; }
        float w0 = 1.f / (1.f + expf(b1 - b0));
        tidx[n * 2] = i0; tidx[n * 2 + 1] = i1;
        tw[n * 2] = w0;   tw[n * 2 + 1] = 1.f - w0;
        atomicAdd(&sC[i0], 1);
        atomicAdd(&sC[i1], 1);
    }
    __syncthreads();
    if (t < 8) {
        atomicAdd(&Psum[t], sP[t]);
        atomicAdd(&cnt8[t], sC[t]);
    }
}

// -------- scatter + fused finalize (aux loss, counts, offs) ----------
__global__ void k_scatter(const int* __restrict__ tidx, const float* __restrict__ Psum,
                          const int* __restrict__ cnt8, int* __restrict__ curs,
                          int* __restrict__ tlist, int* __restrict__ slots,
                          float* __restrict__ out, int* __restrict__ counts,
                          int* __restrict__ offs) {
    __shared__ int s_off[8];
    int t = threadIdx.x;
    if (t == 0) {
        int o = 0;
        for (int e = 0; e < 8; e++) { s_off[e] = o; o += cnt8[e]; }
    }
    __syncthreads();
    if (blockIdx.x == 0 && t == 0) {
        float aux = 0.f;
        for (int e = 0; e < 8; e++) {
            int c = cnt8[e];
            aux += (float)c * Psum[e];
            offs[e] = s_off[e]; counts[e] = c;
        }
        out[OUT_ELEMS] = 8.f * aux / ((float)N_TOK * (float)N_TOK);
        offs[8] = 4096; counts[8] = 2048;
    }
    int n = blockIdx.x * 256 + t;
    if (n < N_TOK) {
#pragma unroll
        for (int k = 0; k < 2; k++) {
            int e = tidx[n * 2 + k];
            int p = atomicAdd(&curs[e], 1);
            int sl = s_off[e] + p;
            tlist[sl] = n;
            slots[n * 2 + k] = sl;
        }
    }
}

// ---------------- GEMM1: gathered X @ [Wg|Wu], fused silu*u -> H bf16 -------
// Double-buffered LDS, one barrier per K-step, prefetch issued right after
// the barrier so it overlaps the ds_read+MFMA phase (latency cover at low occ).
__global__ __launch_bounds__(256, 2)
void k_gemm1(const u16* __restrict__ xb, const u16* __restrict__ wgt,
             const u16* __restrict__ wut, const u16* __restrict__ wsgt,
             const u16* __restrict__ wsut, const int* __restrict__ tlist,
             const int* __restrict__ counts, const int* __restrict__ offs,
             u16* __restrict__ H) {
    int bx = blockIdx.x;
    int job = bx >> 7;
    int mt = (bx >> 3) & 15;
    int nt = bx & 7;
    int jcnt = counts[job];
    int m0 = mt << 7;
    if (m0 >= jcnt) return;
    int joff = offs[job];
    int n0 = nt << 7;
    const u16* Bg = (job < 8) ? (wgt + (size_t)job * 1048576) : wsgt;
    const u16* Bu = (job < 8) ? (wut + (size_t)job * 1048576) : wsut;

    __shared__ __attribute__((aligned(128))) u16 As[8192];   // 2 x 128x32
    __shared__ __attribute__((aligned(128))) u16 Bgs[8192];  // 2 x 4 chunks
    __shared__ __attribute__((aligned(128))) u16 Bus[8192];

    int t = threadIdx.x;
    int wave = t >> 6, lane = t & 63;
    int ch = (lane & 3) * 8;
    int r0 = (wave * 2) * 16 + (lane >> 2);
    int r1 = r0 + 16;
    int tok0 = tlist[joff + m0 + r0];
    int tok1 = tlist[joff + m0 + r1];
    const u16* a0 = xb + (size_t)tok0 * 1024 + ch;
    const u16* a1 = xb + (size_t)tok1 * 1024 + ch;
    const u16* gB = Bg + (size_t)wave * 8192 + (size_t)(n0 + lane) * 8;
    const u16* uB = Bu + (size_t)wave * 8192 + (size_t)(n0 + lane) * 8;

    int wm = (wave >> 1) << 6, wn = (wave & 1) << 6;
    int quad = lane >> 4, lr = lane & 15;

    f32x4 accg[4][4], accu[4][4];
    f32x4 zz = {0.f, 0.f, 0.f, 0.f};
#pragma unroll
    for (int i = 0; i < 4; i++)
#pragma unroll
        for (int j = 0; j < 4; j++) { accg[i][j] = zz; accu[i][j] = zz; }

    auto stage = [&](int bo, int step) {
        int k0 = step * 32;
        size_t koff = (size_t)step * 32768;
        GLDS16(a0 + k0, As + bo + (wave * 2) * 512);
        GLDS16(a1 + k0, As + bo + (wave * 2 + 1) * 512);
        GLDS16(gB + koff,       Bgs + bo + wave * 1024);
        GLDS16(gB + koff + 512, Bgs + bo + wave * 1024 + 512);
        GLDS16(uB + koff,       Bus + bo + wave * 1024);
        GLDS16(uB + koff + 512, Bus + bo + wave * 1024 + 512);
    };
    auto compute = [&](int bo) {
        short8 af[4], bgf[4], bff[4];
#pragma unroll
        for (int i = 0; i < 4; i++) {
            int nrow = wn + i * 16 + lr;
            af[i]  = *(const short8*)(As  + bo + (wm + i * 16 + lr) * 32 + quad * 8);
            bgf[i] = *(const short8*)(Bgs + bo + quad * 1024 + nrow * 8);
            bff[i] = *(const short8*)(Bus + bo + quad * 1024 + nrow * 8);
        }
#pragma unroll
        for (int mi = 0; mi < 4; mi++)
#pragma unroll
            for (int ni = 0; ni < 4; ni++) {
                accg[mi][ni] = __builtin_amdgcn_mfma_f32_16x16x32_bf16(af[mi], bgf[ni], accg[mi][ni], 0, 0, 0);
                accu[mi][ni] = __builtin_amdgcn_mfma_f32_16x16x32_bf16(af[mi], bff[ni], accu[mi][ni], 0, 0, 0);
            }
    };

    stage(0, 0);
#pragma unroll 1
    for (int s = 0; s < 15; s++) {
        __syncthreads();
        stage(4096, 2 * s + 1);
        compute(0);
        __syncthreads();
        stage(0, 2 * s + 2);
        compute(4096);
    }
    __syncthreads();
    stage(4096, 31);
    compute(0);
    __syncthreads();
    compute(4096);

#pragma unroll
    for (int mi = 0; mi < 4; mi++) {
        int rowb = m0 + wm + mi * 16 + quad * 4;
#pragma unroll
        for (int rr = 0; rr < 4; rr++) {
            int row = rowb + rr;
            if (row < jcnt) {
                size_t base = (size_t)(joff + row) * 1024 + n0 + wn;
#pragma unroll
                for (int ni = 0; ni < 4; ni++) {
                    float g = accg[mi][ni][rr];
                    float u = accu[mi][ni][rr];
                    float h = (g / (1.f + expf(-g))) * u;
                    H[base + ni * 16 + lr] = f2bf(h);
                }
            }
        }
    }
}

// ---------------- GEMM2: H @ Wd -> Y bf16 (dbuf pipeline) ----------
__global__ __launch_bounds__(256, 2)
void k_gemm2(const u16* __restrict__ H, const u16* __restrict__ wdt,
             const u16* __restrict__ wsdt, const int* __restrict__ counts,
             const int* __restrict__ offs, u16* __restrict__ Y) {
    int bx = blockIdx.x;
    int job = bx >> 7;
    int mt = (bx >> 3) & 15;
    int nt = bx & 7;
    int jcnt = counts[job];
    int m0 = mt << 7;
    if (m0 >= jcnt) return;
    int joff = offs[job];
    int n0 = nt << 7;
    const u16* Bt = (job < 8) ? (wdt + (size_t)job * 1048576) : wsdt;

    __shared__ __attribute__((aligned(128))) u16 As[8192];
    __shared__ __attribute__((aligned(128))) u16 Bs[8192];

    int t = threadIdx.x;
    int wave = t >> 6, lane = t & 63;
    int ch = (lane & 3) * 8;
    int r0 = (wave * 2) * 16 + (lane >> 2);
    int r1 = r0 + 16;
    const u16* a0 = H + (size_t)(joff + m0 + r0) * 1024 + ch;
    const u16* a1 = H + (size_t)(joff + m0 + r1) * 1024 + ch;
    const u16* bB = Bt + (size_t)wave * 8192 + (size_t)(n0 + lane) * 8;

    int wm = (wave >> 1) << 6, wn = (wave & 1) << 6;
    int quad = lane >> 4, lr = lane & 15;

    f32x4 acc[4][4];
    f32x4 zz = {0.f, 0.f, 0.f, 0.f};
#pragma unroll
    for (int i = 0; i < 4; i++)
#pragma unroll
        for (int j = 0; j < 4; j++) acc[i][j] = zz;

    auto stage = [&](int bo, int step) {
        int k0 = step * 32;
        size_t koff = (size_t)step * 32768;
        GLDS16(a0 + k0, As + bo + (wave * 2) * 512);
        GLDS16(a1 + k0, As + bo + (wave * 2 + 1) * 512);
        GLDS16(bB + koff,       Bs + bo + wave * 1024);
        GLDS16(bB + koff + 512, Bs + bo + wave * 1024 + 512);
    };
    auto compute = [&](int bo) {
        short8 af[4], bf[4];
#pragma unroll
        for (int i = 0; i < 4; i++) {
            af[i] = *(const short8*)(As + bo + (wm + i * 16 + lr) * 32 + quad * 8);
            bf[i] = *(const short8*)(Bs + bo + quad * 1024 + (wn + i * 16 + lr) * 8);
        }
#pragma unroll
        for (int mi = 0; mi < 4; mi++)
#pragma unroll
            for (int ni = 0; ni < 4; ni++)
                acc[mi][ni] = __builtin_amdgcn_mfma_f32_16x16x32_bf16(af[mi], bf[ni], acc[mi][ni], 0, 0, 0);
    };

    stage(0, 0);
#pragma unroll 1
    for (int s = 0; s < 15; s++) {
        __syncthreads();
        stage(4096, 2 * s + 1);
        compute(0);
        __syncthreads();
        stage(0, 2 * s + 2);
        compute(4096);
    }
    __syncthreads();
    stage(4096, 31);
    compute(0);
    __syncthreads();
    compute(4096);

#pragma unroll
    for (int mi = 0; mi < 4; mi++) {
        int rowb = m0 + wm + mi * 16 + quad * 4;
#pragma unroll
        for (int rr = 0; rr < 4; rr++) {
            int row = rowb + rr;
            if (row < jcnt) {
                u16* yrow = Y + (size_t)(joff + row) * 1024 + n0 + wn;
#pragma unroll
                for (int ni = 0; ni < 4; ni++)
                    yrow[ni * 16 + lr] = f2bf(acc[mi][ni][rr]);
            }
        }
    }
}

// ---------------- combine: out[n] = w0*Y[s0] + w1*Y[s1] + Y[4096+n] ---------
__global__ void k_combine(const u16* __restrict__ Y, const int* __restrict__ slots,
                          const float* __restrict__ tw, float* __restrict__ out) {
    int n = blockIdx.x;
    int d = threadIdx.x;
    int s0 = slots[n * 2], s1 = slots[n * 2 + 1];
    float w0 = tw[n * 2], w1 = tw[n * 2 + 1];
    u16x4 y0 = ((const u16x4*)(Y + (size_t)s0 * 1024))[d];
    u16x4 y1 = ((const u16x4*)(Y + (size_t)s1 * 1024))[d];
    u16x4 ys = ((const u16x4*)(Y + (size_t)(4096 + n) * 1024))[d];
    f32x4 r;
    r.x = w0 * bf2f(y0.x) + w1 * bf2f(y1.x) + bf2f(ys.x);
    r.y = w0 * bf2f(y0.y) + w1 * bf2f(y1.y) + bf2f(ys.y);
    r.z = w0 * bf2f(y0.z) + w1 * bf2f(y1.z) + bf2f(ys.z);
    r.w = w0 * bf2f(y0.w) + w1 * bf2f(y1.w) + bf2f(ys.w);
    ((f32x4*)(out + (size_t)n * 1024))[d] = r;
}

extern "C" void kernel_launch(void* const* d_in, const int* in_sizes, int n_in,
                              void* d_out, int out_size, void* d_ws, size_t ws_size,
                              hipStream_t stream) {
    const float* x     = (const float*)d_in[0];
    const float* wgate = (const float*)d_in[1];
    const float* wg    = (const float*)d_in[2];
    const float* wu    = (const float*)d_in[3];
    const float* wd    = (const float*)d_in[4];
    const float* wsg   = (const float*)d_in[5];
    const float* wsu   = (const float*)d_in[6];
    const float* wsd   = (const float*)d_in[7];
    float* out = (float*)d_out;

    char* ws = (char*)d_ws;
    u16*   xb    = (u16*)(ws + 0);           // 4 MB
    u16*   wgt   = (u16*)(ws + 4194304);     // 16 MB
    u16*   wut   = (u16*)(ws + 20971520);    // 16 MB
    u16*   wdt   = (u16*)(ws + 37748736);    // 16 MB
    u16*   wsgt  = (u16*)(ws + 54525952);    // 2 MB
    u16*   wsut  = (u16*)(ws + 56623104);    // 2 MB
    u16*   wsdt  = (u16*)(ws + 58720256);    // 2 MB
    u16*   H     = (u16*)(ws + 60817408);    // 12 MB
    // Y (bf16) overlays wgt (dead after gemm1; gemm2 runs strictly after)
    u16*   Y     = (u16*)(ws + 4194304);     // 12.58 MB
    int*   tidx  = (int*)(ws + 73400320);
    float* tw    = (float*)(ws + 73416704);
    int*   tlist = (int*)(ws + 73433088);
    int*   slots = (int*)(ws + 73457664);
    int*   counts= (int*)(ws + 73474048);
    int*   offs  = (int*)(ws + 73474112);
    int*   curs  = (int*)(ws + 73474176);
    float* Psum  = (float*)(ws + 73474240);
    int*   cnt8  = (int*)(ws + 73474304);

    k_init<<<8, 256, 0, stream>>>(tlist, curs, Psum, cnt8);
    k_router<<<512, 256, 0, stream>>>(x, wgate, xb, tidx, tw, Psum, cnt8);
    k_scatter<<<8, 256, 0, stream>>>(tidx, Psum, cnt8, curs, tlist, slots,
                                     out, counts, offs);
    k_cvt_w<<<3456, 256, 0, stream>>>(wg, wu, wd, wsg, wsu, wsd,
                                      wgt, wut, wdt, wsgt, wsut, wsdt);
    k_gemm1<<<1152, 256, 0, stream>>>(xb, wgt, wut, wsgt, wsut, tlist, counts, offs, H);
    k_gemm2<<<1152, 256, 0, stream>>>(H, wdt, wsdt, counts, offs, Y);
    k_combine<<<2048, 256, 0, stream>>>(Y, slots, tw, out);
}

// Round 8
// 274.230 us; speedup vs baseline: 1.0070x; 1.0070x over previous
//
#include <hip/hip_runtime.h>
#include <math.h>

typedef unsigned short u16;
typedef __attribute__((ext_vector_type(8))) short short8;
typedef __attribute__((ext_vector_type(4))) float f32x4;
typedef __attribute__((ext_vector_type(4))) unsigned short u16x4;
typedef __attribute__((ext_vector_type(8))) unsigned short u16x8;

#define N_TOK 2048
#define DIM 1024
#define OUT_ELEMS 2097152   // N_TOK * DIM

#define GLDS16(gp, lp) __builtin_amdgcn_global_load_lds( \
    (const __attribute__((address_space(1))) unsigned int*)(gp), \
    (__attribute__((address_space(3))) unsigned int*)(lp), 16, 0, 0)

__device__ __forceinline__ u16 f2bf(float f) {
    union { float f; unsigned u; } v; v.f = f;
    unsigned r = (v.u + 0x7FFFu + ((v.u >> 16) & 1u)) >> 16;
    return (u16)r;
}
__device__ __forceinline__ float bf2f(u16 h) {
    union { unsigned u; float f; } v; v.u = ((unsigned)h) << 16;
    return v.f;
}

// -------- init: shared token list, cursors, Psum/cnt zeros ------
__global__ void k_init(int* __restrict__ tlist, int* __restrict__ curs,
                       float* __restrict__ Psum, int* __restrict__ cnt8) {
    int i = blockIdx.x * 256 + threadIdx.x;   // 0..2047
    tlist[4096 + i] = i;
    if (i < 16) curs[i] = 0;
    if (i < 8) { Psum[i] = 0.f; cnt8[i] = 0; }
}

// ------- weights: fp32 [K,N] -> bf16 CHUNK-TRANSPOSED W'[k/8][n][8] -------
__global__ void k_cvt_w(const float* __restrict__ wg, const float* __restrict__ wu,
                        const float* __restrict__ wd, const float* __restrict__ wsg,
                        const float* __restrict__ wsu, const float* __restrict__ wsd,
                        u16* __restrict__ wgt, u16* __restrict__ wut,
                        u16* __restrict__ wdt, u16* __restrict__ wsgt,
                        u16* __restrict__ wsut, u16* __restrict__ wsdt) {
    __shared__ u16 tile[8 * 1024];   // 16 KB
    int bx = blockIdx.x;             // 27 * 128
    int mat = bx >> 7;
    int chunk = bx & 127;            // k-chunk (8 rows)
    const float* src; u16* dst;
    if      (mat <  8) { src = wg  + (size_t)mat * 1048576;        dst = wgt + (size_t)mat * 1048576; }
    else if (mat < 16) { src = wu  + (size_t)(mat - 8) * 1048576;  dst = wut + (size_t)(mat - 8) * 1048576; }
    else if (mat < 24) { src = wd  + (size_t)(mat - 16) * 1048576; dst = wdt + (size_t)(mat - 16) * 1048576; }
    else if (mat == 24){ src = wsg; dst = wsgt; }
    else if (mat == 25){ src = wsu; dst = wsut; }
    else               { src = wsd; dst = wsdt; }
    const float* srow = src + (size_t)chunk * 8192;   // 8 rows of 1024
    u16* dchunk = dst + (size_t)chunk * 8192;         // 16KB contiguous out
    int t = threadIdx.x;
    int r  = t >> 5;                 // 0..7
    int c0 = (t & 31) * 4;           // 0..124
    f32x4 v[8];
#pragma unroll
    for (int j = 0; j < 8; j++)
        v[j] = __builtin_nontemporal_load((const f32x4*)(srow + r * 1024 + c0 + j * 128));
#pragma unroll
    for (int j = 0; j < 8; j++) {
        u16x4 o;
        o.x = f2bf(v[j].x); o.y = f2bf(v[j].y); o.z = f2bf(v[j].z); o.w = f2bf(v[j].w);
        *(u16x4*)(tile + r * 1024 + c0 + j * 128) = o;
    }
    __syncthreads();
#pragma unroll
    for (int j = 0; j < 4; j++) {
        int n = t + j * 256;
        u16x8 o;
#pragma unroll
        for (int k = 0; k < 8; k++) o[k] = tile[k * 1024 + n];
        *(u16x8*)(dchunk + n * 8) = o;
    }
}

// -------- router: logits, top-2, Psum/counts, fused x->bf16 --------
__global__ void k_router(const float* __restrict__ x, const float* __restrict__ wgate,
                         u16* __restrict__ xb, int* __restrict__ tidx,
                         float* __restrict__ tw, float* __restrict__ Psum,
                         int* __restrict__ cnt8) {
    __shared__ float sP[8];
    __shared__ int   sC[8];
    int t = threadIdx.x;
    if (t < 8) { sP[t] = 0.f; sC[t] = 0; }
    __syncthreads();
    int wave = t >> 6;
    int lane = t & 63;
    int n = blockIdx.x * 4 + wave;
    const float* xr = x + (size_t)n * DIM;
    u16* xbr = xb + (size_t)n * DIM;
    float acc[8] = {0.f,0.f,0.f,0.f,0.f,0.f,0.f,0.f};
#pragma unroll
    for (int i = 0; i < 16; i++) {
        int d = lane + i * 64;
        float xv = xr[d];
        xbr[d] = f2bf(xv);
        const float* wr = wgate + d * 8;
#pragma unroll
        for (int e = 0; e < 8; e++) acc[e] += xv * wr[e];
    }
#pragma unroll
    for (int off = 32; off; off >>= 1) {
#pragma unroll
        for (int e = 0; e < 8; e++) acc[e] += __shfl_xor(acc[e], off);
    }
    if (lane == 0) {
        float mx = acc[0];
#pragma unroll
        for (int e = 1; e < 8; e++) mx = fmaxf(mx, acc[e]);
        float p[8], s = 0.f;
#pragma unroll
        for (int e = 0; e < 8; e++) { p[e] = expf(acc[e] - mx); s += p[e]; }
        float inv = 1.f / s;
#pragma unroll
        for (int e = 0; e < 8; e++) atomicAdd(&sP[e], p[e] * inv);
        int i0 = 0; float b0 = acc[0];
#pragma unroll
        for (int e = 1; e < 8; e++) if (acc[e] > b0) { b0 = acc[e]; i0 = e; }
        int i1 = -1; float b1 = -3.4e38f;
#pragma unroll
        for (int e = 0; e < 8; e++) if (e != i0 && acc[e] > b1) { b1 = acc[e]; i1 = e; }
        float w0 = 1.f / (1.f + expf(b1 - b0));
        tidx[n * 2] = i0; tidx[n * 2 + 1] = i1;
        tw[n * 2] = w0;   tw[n * 2 + 1] = 1.f - w0;
        atomicAdd(&sC[i0], 1);
        atomicAdd(&sC[i1], 1);
    }
    __syncthreads();
    if (t < 8) {
        atomicAdd(&Psum[t], sP[t]);
        atomicAdd(&cnt8[t], sC[t]);
    }
}

// -------- scatter + fused finalize (aux loss, counts, offs) ----------
__global__ void k_scatter(const int* __restrict__ tidx, const float* __restrict__ Psum,
                          const int* __restrict__ cnt8, int* __restrict__ curs,
                          int* __restrict__ tlist, int* __restrict__ slots,
                          float* __restrict__ out, int* __restrict__ counts,
                          int* __restrict__ offs) {
    __shared__ int s_off[8];
    int t = threadIdx.x;
    if (t == 0) {
        int o = 0;
        for (int e = 0; e < 8; e++) { s_off[e] = o; o += cnt8[e]; }
    }
    __syncthreads();
    if (blockIdx.x == 0 && t == 0) {
        float aux = 0.f;
        for (int e = 0; e < 8; e++) {
            int c = cnt8[e];
            aux += (float)c * Psum[e];
            offs[e] = s_off[e]; counts[e] = c;
        }
        out[OUT_ELEMS] = 8.f * aux / ((float)N_TOK * (float)N_TOK);
        offs[8] = 4096; counts[8] = 2048;
    }
    int n = blockIdx.x * 256 + t;
    if (n < N_TOK) {
#pragma unroll
        for (int k = 0; k < 2; k++) {
            int e = tidx[n * 2 + k];
            int p = atomicAdd(&curs[e], 1);
            int sl = s_off[e] + p;
            tlist[sl] = n;
            slots[n * 2 + k] = sl;
        }
    }
}

// ------- GEMM1: gathered X @ [Wg|Wu], silu*u -> H bf16. 128x64 tile -------
// dbuf LDS, 1 barrier/K-step. 2304 blocks (~768 working, 3/CU).
__global__ __launch_bounds__(256, 3)
void k_gemm1(const u16* __restrict__ xb, const u16* __restrict__ wgt,
             const u16* __restrict__ wut, const u16* __restrict__ wsgt,
             const u16* __restrict__ wsut, const int* __restrict__ tlist,
             const int* __restrict__ counts, const int* __restrict__ offs,
             u16* __restrict__ H) {
    int bx = blockIdx.x;
    int job = bx >> 8;
    int mt = (bx >> 4) & 15;
    int nt = bx & 15;
    int jcnt = counts[job];
    int m0 = mt << 7;
    if (m0 >= jcnt) return;
    int joff = offs[job];
    int n0 = nt << 6;
    const u16* Bg = (job < 8) ? (wgt + (size_t)job * 1048576) : wsgt;
    const u16* Bu = (job < 8) ? (wut + (size_t)job * 1048576) : wsut;

    __shared__ __attribute__((aligned(128))) u16 As[8192];   // 2 x 128x32
    __shared__ __attribute__((aligned(128))) u16 Bgs[4096];  // 2 x 4x512
    __shared__ __attribute__((aligned(128))) u16 Bus[4096];

    int t = threadIdx.x;
    int wave = t >> 6, lane = t & 63;
    int ch = (lane & 3) * 8;
    int r0 = wave * 32 + (lane >> 2);
    int r1 = r0 + 16;
    int tok0 = tlist[joff + m0 + r0];
    int tok1 = tlist[joff + m0 + r1];
    const u16* a0 = xb + (size_t)tok0 * 1024 + ch;
    const u16* a1 = xb + (size_t)tok1 * 1024 + ch;
    const u16* gB = Bg + (size_t)wave * 8192 + (size_t)(n0 + lane) * 8;
    const u16* uB = Bu + (size_t)wave * 8192 + (size_t)(n0 + lane) * 8;

    int wm = (wave >> 1) << 6, wn = (wave & 1) << 5;
    int quad = lane >> 4, lr = lane & 15;

    f32x4 accg[4][2], accu[4][2];
    f32x4 zz = {0.f, 0.f, 0.f, 0.f};
#pragma unroll
    for (int i = 0; i < 4; i++)
#pragma unroll
        for (int j = 0; j < 2; j++) { accg[i][j] = zz; accu[i][j] = zz; }

    auto stage = [&](int bo, int step) {
        int k0 = step * 32;
        size_t koff = (size_t)step * 32768;   // 4 chunks * 8192 u16
        GLDS16(a0 + k0, As + bo * 2 + wave * 1024);
        GLDS16(a1 + k0, As + bo * 2 + wave * 1024 + 512);
        GLDS16(gB + koff, Bgs + bo + wave * 512);
        GLDS16(uB + koff, Bus + bo + wave * 512);
    };
    auto compute = [&](int bo) {
        short8 af[4], bgf[2], bff[2];
#pragma unroll
        for (int i = 0; i < 4; i++)
            af[i] = *(const short8*)(As + bo * 2 + (wm + i * 16 + lr) * 32 + quad * 8);
#pragma unroll
        for (int i = 0; i < 2; i++) {
            int nrow = wn + i * 16 + lr;
            bgf[i] = *(const short8*)(Bgs + bo + quad * 512 + nrow * 8);
            bff[i] = *(const short8*)(Bus + bo + quad * 512 + nrow * 8);
        }
#pragma unroll
        for (int mi = 0; mi < 4; mi++)
#pragma unroll
            for (int ni = 0; ni < 2; ni++) {
                accg[mi][ni] = __builtin_amdgcn_mfma_f32_16x16x32_bf16(af[mi], bgf[ni], accg[mi][ni], 0, 0, 0);
                accu[mi][ni] = __builtin_amdgcn_mfma_f32_16x16x32_bf16(af[mi], bff[ni], accu[mi][ni], 0, 0, 0);
            }
    };

    stage(0, 0);
#pragma unroll 1
    for (int s = 0; s < 15; s++) {
        __syncthreads();
        stage(2048, 2 * s + 1);
        compute(0);
        __syncthreads();
        stage(0, 2 * s + 2);
        compute(2048);
    }
    __syncthreads();
    stage(2048, 31);
    compute(0);
    __syncthreads();
    compute(2048);

#pragma unroll
    for (int mi = 0; mi < 4; mi++) {
        int rowb = m0 + wm + mi * 16 + quad * 4;
#pragma unroll
        for (int rr = 0; rr < 4; rr++) {
            int row = rowb + rr;
            if (row < jcnt) {
                size_t base = (size_t)(joff + row) * 1024 + n0 + wn;
#pragma unroll
                for (int ni = 0; ni < 2; ni++) {
                    float g = accg[mi][ni][rr];
                    float u = accu[mi][ni][rr];
                    float h = (g / (1.f + expf(-g))) * u;
                    H[base + ni * 16 + lr] = f2bf(h);
                }
            }
        }
    }
}

// ---------------- GEMM2: H @ Wd -> Y bf16. 128x64 tile, dbuf ----------
__global__ __launch_bounds__(256, 3)
void k_gemm2(const u16* __restrict__ H, const u16* __restrict__ wdt,
             const u16* __restrict__ wsdt, const int* __restrict__ counts,
             const int* __restrict__ offs, u16* __restrict__ Y) {
    int bx = blockIdx.x;
    int job = bx >> 8;
    int mt = (bx >> 4) & 15;
    int nt = bx & 15;
    int jcnt = counts[job];
    int m0 = mt << 7;
    if (m0 >= jcnt) return;
    int joff = offs[job];
    int n0 = nt << 6;
    const u16* Bt = (job < 8) ? (wdt + (size_t)job * 1048576) : wsdt;

    __shared__ __attribute__((aligned(128))) u16 As[8192];
    __shared__ __attribute__((aligned(128))) u16 Bs[4096];

    int t = threadIdx.x;
    int wave = t >> 6, lane = t & 63;
    int ch = (lane & 3) * 8;
    int r0 = wave * 32 + (lane >> 2);
    int r1 = r0 + 16;
    const u16* a0 = H + (size_t)(joff + m0 + r0) * 1024 + ch;
    const u16* a1 = H + (size_t)(joff + m0 + r1) * 1024 + ch;
    const u16* bB = Bt + (size_t)wave * 8192 + (size_t)(n0 + lane) * 8;

    int wm = (wave >> 1) << 6, wn = (wave & 1) << 5;
    int quad = lane >> 4, lr = lane & 15;

    f32x4 acc[4][2];
    f32x4 zz = {0.f, 0.f, 0.f, 0.f};
#pragma unroll
    for (int i = 0; i < 4; i++)
#pragma unroll
        for (int j = 0; j < 2; j++) acc[i][j] = zz;

    auto stage = [&](int bo, int step) {
        int k0 = step * 32;
        size_t koff = (size_t)step * 32768;
        GLDS16(a0 + k0, As + bo * 2 + wave * 1024);
        GLDS16(a1 + k0, As + bo * 2 + wave * 1024 + 512);
        GLDS16(bB + koff, Bs + bo + wave * 512);
    };
    auto compute = [&](int bo) {
        short8 af[4], bf[2];
#pragma unroll
        for (int i = 0; i < 4; i++)
            af[i] = *(const short8*)(As + bo * 2 + (wm + i * 16 + lr) * 32 + quad * 8);
#pragma unroll
        for (int i = 0; i < 2; i++)
            bf[i] = *(const short8*)(Bs + bo + quad * 512 + (wn + i * 16 + lr) * 8);
#pragma unroll
        for (int mi = 0; mi < 4; mi++)
#pragma unroll
            for (int ni = 0; ni < 2; ni++)
                acc[mi][ni] = __builtin_amdgcn_mfma_f32_16x16x32_bf16(af[mi], bf[ni], acc[mi][ni], 0, 0, 0);
    };

    stage(0, 0);
#pragma unroll 1
    for (int s = 0; s < 15; s++) {
        __syncthreads();
        stage(2048, 2 * s + 1);
        compute(0);
        __syncthreads();
        stage(0, 2 * s + 2);
        compute(2048);
    }
    __syncthreads();
    stage(2048, 31);
    compute(0);
    __syncthreads();
    compute(2048);

#pragma unroll
    for (int mi = 0; mi < 4; mi++) {
        int rowb = m0 + wm + mi * 16 + quad * 4;
#pragma unroll
        for (int rr = 0; rr < 4; rr++) {
            int row = rowb + rr;
            if (row < jcnt) {
                u16* yrow = Y + (size_t)(joff + row) * 1024 + n0 + wn;
#pragma unroll
                for (int ni = 0; ni < 2; ni++)
                    yrow[ni * 16 + lr] = f2bf(acc[mi][ni][rr]);
            }
        }
    }
}

// ---------------- combine: out[n] = w0*Y[s0] + w1*Y[s1] + Y[4096+n] ---------
__global__ void k_combine(const u16* __restrict__ Y, const int* __restrict__ slots,
                          const float* __restrict__ tw, float* __restrict__ out) {
    int n = blockIdx.x;
    int d = threadIdx.x;
    int s0 = slots[n * 2], s1 = slots[n * 2 + 1];
    float w0 = tw[n * 2], w1 = tw[n * 2 + 1];
    u16x4 y0 = ((const u16x4*)(Y + (size_t)s0 * 1024))[d];
    u16x4 y1 = ((const u16x4*)(Y + (size_t)s1 * 1024))[d];
    u16x4 ys = ((const u16x4*)(Y + (size_t)(4096 + n) * 1024))[d];
    f32x4 r;
    r.x = w0 * bf2f(y0.x) + w1 * bf2f(y1.x) + bf2f(ys.x);
    r.y = w0 * bf2f(y0.y) + w1 * bf2f(y1.y) + bf2f(ys.y);
    r.z = w0 * bf2f(y0.z) + w1 * bf2f(y1.z) + bf2f(ys.z);
    r.w = w0 * bf2f(y0.w) + w1 * bf2f(y1.w) + bf2f(ys.w);
    ((f32x4*)(out + (size_t)n * 1024))[d] = r;
}

extern "C" void kernel_launch(void* const* d_in, const int* in_sizes, int n_in,
                              void* d_out, int out_size, void* d_ws, size_t ws_size,
                              hipStream_t stream) {
    const float* x     = (const float*)d_in[0];
    const float* wgate = (const float*)d_in[1];
    const float* wg    = (const float*)d_in[2];
    const float* wu    = (const float*)d_in[3];
    const float* wd    = (const float*)d_in[4];
    const float* wsg   = (const float*)d_in[5];
    const float* wsu   = (const float*)d_in[6];
    const float* wsd   = (const float*)d_in[7];
    float* out = (float*)d_out;

    char* ws = (char*)d_ws;
    u16*   xb    = (u16*)(ws + 0);           // 4 MB
    u16*   wgt   = (u16*)(ws + 4194304);     // 16 MB
    u16*   wut   = (u16*)(ws + 20971520);    // 16 MB
    u16*   wdt   = (u16*)(ws + 37748736);    // 16 MB
    u16*   wsgt  = (u16*)(ws + 54525952);    // 2 MB
    u16*   wsut  = (u16*)(ws + 56623104);    // 2 MB
    u16*   wsdt  = (u16*)(ws + 58720256);    // 2 MB
    u16*   H     = (u16*)(ws + 60817408);    // 12 MB
    // Y (bf16) overlays wgt (dead after gemm1; gemm2 runs strictly after)
    u16*   Y     = (u16*)(ws + 4194304);     // 12.58 MB
    int*   tidx  = (int*)(ws + 73400320);
    float* tw    = (float*)(ws + 73416704);
    int*   tlist = (int*)(ws + 73433088);
    int*   slots = (int*)(ws + 73457664);
    int*   counts= (int*)(ws + 73474048);
    int*   offs  = (int*)(ws + 73474112);
    int*   curs  = (int*)(ws + 73474176);
    float* Psum  = (float*)(ws + 73474240);
    int*   cnt8  = (int*)(ws + 73474304);

    k_init<<<8, 256, 0, stream>>>(tlist, curs, Psum, cnt8);
    k_router<<<512, 256, 0, stream>>>(x, wgate, xb, tidx, tw, Psum, cnt8);
    k_scatter<<<8, 256, 0, stream>>>(tidx, Psum, cnt8, curs, tlist, slots,
                                     out, counts, offs);
    k_cvt_w<<<3456, 256, 0, stream>>>(wg, wu, wd, wsg, wsu, wsd,
                                      wgt, wut, wdt, wsgt, wsut, wsdt);
    k_gemm1<<<2304, 256, 0, stream>>>(xb, wgt, wut, wsgt, wsut, tlist, counts, offs, H);
    k_gemm2<<<2304, 256, 0, stream>>>(H, wdt, wsdt, counts, offs, Y);
    k_combine<<<2048, 256, 0, stream>>>(Y, slots, tw, out);
}